// Round 8
// baseline (388.208 us; speedup 1.0000x reference)
//
#include <hip/hip_runtime.h>
#include <cstdint>
#include <cstddef>

// ---------------------------------------------------------------------------
// LSTM cell + 3-layer decoder, MI355X (gfx950)
// B=8192, H=1024, D_IN=1024, D1=512, D2=341(pad 384), A=512
// R13: resubmit of R12 after infra-side container failure (no counters came
// back). R12 = R7 gates geometry (BK=32, 256x256, 3-buf, counted vmcnt(4))
// with the two in-loop asm lgkmcnt(0)+sched_barrier drains REMOVED: our
// ds_reads are compiler-visible C++ loads, so hipcc emits counted lgkmcnt
// waits per-MFMA (m97 behavior); the blanket drain forced a full 12-read
// wait twice per tile inside the barrier-locked phase.
// prep_pack/prep_small/fused_decoder: R9 forms (best total 384.3).
// FRAG(K) addr(row,k) = (row>>4)*16K + (k>>5)*512 + ((k>>3)&3)*128
//                       + (row&15)*8 + (k&7)   [halves]
// ---------------------------------------------------------------------------

typedef _Float16 half_t;
typedef _Float16 half8 __attribute__((ext_vector_type(8)));
typedef _Float16 half4v __attribute__((ext_vector_type(4)));
typedef float float4v __attribute__((ext_vector_type(4)));

#define GLD_LDS16(gptr, lptr)                                                  \
  __builtin_amdgcn_global_load_lds(                                            \
      (const __attribute__((address_space(1))) void*)(gptr),                   \
      (__attribute__((address_space(3))) void*)(lptr), 16, 0, 0)

__device__ __forceinline__ float fsig(float x) {
  return 1.0f / (1.0f + __expf(-x));
}
__device__ __forceinline__ float ftanh_(float x) {
  const float e = __expf(2.0f * x);
  return 1.0f - 2.0f / (e + 1.0f);
}

// ---------------------------------------------------------------------------
// Gates GEMM with fused LSTM epilogue.
// 256x256 tile, BK=32, 512 threads (8 waves, 2M x 4N of 128x64 each).
// LDS: 3 buffers x (A 16KB + B 16KB) = 96 KB. Prefetch distance 2 K-tiles;
// counted vmcnt(4); 2 phases/K-tile with 4 barriers (fine interleave).
// NO explicit lgkm drains — compiler emits counted lgkmcnt per MFMA.
// Writes h_out (f32 row-major) and H2F (f16, FRAG(1024) order).
// ---------------------------------------------------------------------------
__global__ __launch_bounds__(512, 2) void gemm_gates(const half_t* __restrict__ A,
                                                     const half_t* __restrict__ Bw,
                                                     const float* __restrict__ bias,
                                                     const float* __restrict__ cin,
                                                     float* __restrict__ hout,
                                                     half_t* __restrict__ h2f) {
  constexpr int K = 2048;
  constexpr int NT = 64;  // K / 32
  __shared__ alignas(16) half_t As[3][256 * 32];
  __shared__ alignas(16) half_t Bs[3][256 * 32];
  const int tid = threadIdx.x;
  const int lane = tid & 63;
  const int wave = tid >> 6;
  const int m = lane & 15;
  const int q = lane >> 4;
  const int ks = (q ^ ((m >> 1) & 3)) << 3;  // swizzled k-chunk (halves)
  const int wm = (wave >> 2) << 7;           // 0 / 128
  const int wn = (wave & 3) << 6;            // 0 / 64 / 128 / 192

  const int bid = blockIdx.x;
  const int xcd = bid & 7;
  const int l = bid >> 3;  // 0..63
  const size_t tile_n = (size_t)((xcd << 1) | (l & 1)) << 8;
  const size_t tile_m = (size_t)(l >> 1) << 8;

  const int ci0 = tid, ci1 = tid + 512;
  const int r0 = ci0 >> 2, k0s = (ci0 & 3) ^ ((r0 >> 1) & 3);
  const int r1 = ci1 >> 2, k1s = (ci1 & 3) ^ ((r1 >> 1) & 3);
  const half_t* Ag0 = A + (tile_m + r0) * (size_t)K + k0s * 8;
  const half_t* Ag1 = A + (tile_m + r1) * (size_t)K + k1s * 8;
  const half_t* Bg0 = Bw + (tile_n + r0) * (size_t)K + k0s * 8;
  const half_t* Bg1 = Bw + (tile_n + r1) * (size_t)K + k1s * 8;
  const int p0 = ci0 * 16, p1 = ci1 * 16;

  // prologue: stage K-tiles 0 and 1; wait only for tile 0 (vmcnt(4)).
  GLD_LDS16(Ag0, (char*)As[0] + p0);
  GLD_LDS16(Ag1, (char*)As[0] + p1);
  GLD_LDS16(Bg0, (char*)Bs[0] + p0);
  GLD_LDS16(Bg1, (char*)Bs[0] + p1);
  GLD_LDS16(Ag0 + 32, (char*)As[1] + p0);
  GLD_LDS16(Ag1 + 32, (char*)As[1] + p1);
  GLD_LDS16(Bg0 + 32, (char*)Bs[1] + p0);
  GLD_LDS16(Bg1 + 32, (char*)Bs[1] + p1);
  asm volatile("s_waitcnt vmcnt(4)" ::: "memory");
  __builtin_amdgcn_s_barrier();
  __builtin_amdgcn_sched_barrier(0);

  float4v acc[8][4] = {};
  int bc = 0;  // buffer of current K-tile
  for (int t = 0; t < NT; ++t) {
    const half_t* as = As[bc];
    const half_t* bs = Bs[bc];
    const int bst = (bc + 2 >= 3) ? bc - 1 : bc + 2;  // (bc+2)%3
    const size_t koff = (size_t)(t + 2) * 32;
    half8 af[4], bf[4];
    // ---- phase 0: rows [wm, wm+64) x all 4 n-frags ----
#pragma unroll
    for (int i = 0; i < 4; ++i)
      af[i] = *(const half8*)(as + (wm + i * 16 + m) * 32 + ks);
#pragma unroll
    for (int j = 0; j < 4; ++j)
      bf[j] = *(const half8*)(bs + (wn + j * 16 + m) * 32 + ks);
    if (t < NT - 2) {
      GLD_LDS16(Ag0 + koff, (char*)As[bst] + p0);
      GLD_LDS16(Ag1 + koff, (char*)As[bst] + p1);
    }
    __builtin_amdgcn_s_barrier();
    // no lgkm drain: ds_read->MFMA is dataflow; compiler emits counted waits
    __builtin_amdgcn_s_setprio(1);
#pragma unroll
    for (int i = 0; i < 4; ++i)
#pragma unroll
      for (int j = 0; j < 4; ++j)
        acc[i][j] = __builtin_amdgcn_mfma_f32_16x16x32_f16(af[i], bf[j],
                                                           acc[i][j], 0, 0, 0);
    __builtin_amdgcn_s_setprio(0);
    __builtin_amdgcn_s_barrier();
    __builtin_amdgcn_sched_barrier(0);
    // ---- phase 1: rows [wm+64, wm+128) x all 4 n-frags (bf reused) ----
    half8 ag[4];
#pragma unroll
    for (int i = 0; i < 4; ++i)
      ag[i] = *(const half8*)(as + (wm + 64 + i * 16 + m) * 32 + ks);
    if (t < NT - 2) {
      GLD_LDS16(Bg0 + koff, (char*)Bs[bst] + p0);
      GLD_LDS16(Bg1 + koff, (char*)Bs[bst] + p1);
    }
    __builtin_amdgcn_s_barrier();
    __builtin_amdgcn_s_setprio(1);
#pragma unroll
    for (int i = 0; i < 4; ++i)
#pragma unroll
      for (int j = 0; j < 4; ++j)
        acc[4 + i][j] = __builtin_amdgcn_mfma_f32_16x16x32_f16(
            ag[i], bf[j], acc[4 + i][j], 0, 0, 0);
    __builtin_amdgcn_s_setprio(0);
    // counted per-tile wait: tile t+1 landed, tile t+2 stays in flight.
    if (t < NT - 2) {
      asm volatile("s_waitcnt vmcnt(4)" ::: "memory");
    } else if (t == NT - 2) {
      asm volatile("s_waitcnt vmcnt(0)" ::: "memory");
    }
    __builtin_amdgcn_s_barrier();
    __builtin_amdgcn_sched_barrier(0);
    bc = (bc + 1 == 3) ? 0 : bc + 1;
  }

  // fused LSTM epilogue (C/D: col=lane&15, row=q*4+reg [m89])
  const int nwave = (int)tile_n + wn;
  const int u = ((nwave >> 6) << 4) + m;  // hidden unit index
  const int rtb = (int)((tile_m + wm) >> 4);
  const int ubase = (u >> 5) * 512 + ((u >> 3) & 3) * 128 + (u & 7);
  float bg[4];
#pragma unroll
  for (int g = 0; g < 4; ++g) bg[g] = bias[nwave + g * 16 + m];
#pragma unroll
  for (int i = 0; i < 8; ++i) {
#pragma unroll
    for (int r = 0; r < 4; ++r) {
      const size_t row = tile_m + wm + q * 4 + i * 16 + r;
      const size_t off = row * 1024 + u;
      const float F = fsig(acc[i][0][r] + bg[0]);
      const float I = fsig(acc[i][1][r] + bg[1]);
      const float S = ftanh_(acc[i][2][r] + bg[2]);
      const float O = fsig(acc[i][3][r] + bg[3]);
      const float cn = cin[off] * F + I * S;
      const float hn = O * ftanh_(cn);
      hout[off] = hn;
      h2f[(size_t)(rtb + i) * 16384 + ubase + (q * 4 + r) * 8] = (half_t)hn;
    }
  }
}

// ---------------------------------------------------------------------------
// Fused decoder (R9 form): dec1(1024->512,tanh) + dec2(512->384,tanh) +
// dec3(384->512) + softmax. 32 batch rows per block, 256 blocks (1/CU).
// Activations in LDS: A1 64KB -> A2 32KB -> A3 24KB; logits alias A1.
// Weights pre-packed B-FRAG (prep_small) -> coalesced 1KB wave reads.
// ---------------------------------------------------------------------------
__global__ __launch_bounds__(512, 2) void fused_decoder(
    const half_t* __restrict__ h2f,  // FRAG(1024), 512 row-tiles
    const half_t* __restrict__ W1f,  // BFRAG(1024): 32 col-tiles x 16384
    const float* __restrict__ b1,    // [512]
    const half_t* __restrict__ W2f,  // BFRAG(512):  24 col-tiles x 8192
    const float* __restrict__ b2,    // [384] (padded, zeros past 341)
    const half_t* __restrict__ W3f,  // BFRAG(384):  32 col-tiles x 6144
    const float* __restrict__ b3,    // [512]
    float* __restrict__ out) {       // [8192][512] f32
  __shared__ alignas(16) half_t A1s[2 * 16384];  // 64KB (aliased by logits)
  __shared__ alignas(16) half_t A2s[2 * 8192];   // 32KB
  __shared__ alignas(16) half_t A3s[2 * 6144];   // 24KB
  float* LOGL = (float*)A1s;                     // [32][512] f32

  const int tid = threadIdx.x;
  const int lane = tid & 63;
  const int w = tid >> 6;  // wave 0..7
  const int m = lane & 15;
  const int q = lane >> 4;
  const int b = blockIdx.x;  // rows b*32 .. b*32+31 (row-tiles 2b, 2b+1)

  // ---- stage A1: 64KB contiguous from H2F (FRAG order preserved) ----
  const half_t* src = h2f + (size_t)b * 32768;
#pragma unroll
  for (int it = 0; it < 8; ++it)
    GLD_LDS16(src + (it * 512 + tid) * 8, (char*)A1s + (it * 512 + tid) * 16);
  asm volatile("s_waitcnt vmcnt(0)" ::: "memory");
  __syncthreads();

  // ---- dec1: K=1024, wave cols [w*64, w*64+64) ----
  {
    float4v acc[2][4] = {};
    const half_t* w1 = W1f + (size_t)(w * 4) * 16384 + lane * 8;
#pragma unroll 2
    for (int c = 0; c < 32; ++c) {
      half8 wf[4], af[2];
#pragma unroll
      for (int j = 0; j < 4; ++j)
        wf[j] = *(const half8*)(w1 + j * 16384 + c * 512);
#pragma unroll
      for (int rt = 0; rt < 2; ++rt)
        af[rt] = *(const half8*)(A1s + rt * 16384 + c * 512 + q * 128 + m * 8);
#pragma unroll
      for (int rt = 0; rt < 2; ++rt)
#pragma unroll
        for (int j = 0; j < 4; ++j)
          acc[rt][j] = __builtin_amdgcn_mfma_f32_16x16x32_f16(af[rt], wf[j],
                                                              acc[rt][j], 0, 0, 0);
    }
    // epilogue: tanh + bias -> A2 (FRAG(512))
#pragma unroll
    for (int j = 0; j < 4; ++j) {
      const int col = w * 64 + j * 16 + m;
      const float bv = b1[col];
      const int cb = (col >> 5) * 512 + ((col >> 3) & 3) * 128 + (col & 7);
#pragma unroll
      for (int rt = 0; rt < 2; ++rt)
#pragma unroll
        for (int r = 0; r < 4; ++r)
          A2s[rt * 8192 + cb + (q * 4 + r) * 8] = (half_t)ftanh_(acc[rt][j][r] + bv);
    }
  }
  __syncthreads();

  // ---- dec2: K=512, wave cols [w*48, w*48+48) ----
  {
    float4v acc[2][3] = {};
    const half_t* w2 = W2f + (size_t)(w * 3) * 8192 + lane * 8;
#pragma unroll 2
    for (int c = 0; c < 16; ++c) {
      half8 wf[3], af[2];
#pragma unroll
      for (int j = 0; j < 3; ++j)
        wf[j] = *(const half8*)(w2 + j * 8192 + c * 512);
#pragma unroll
      for (int rt = 0; rt < 2; ++rt)
        af[rt] = *(const half8*)(A2s + rt * 8192 + c * 512 + q * 128 + m * 8);
#pragma unroll
      for (int rt = 0; rt < 2; ++rt)
#pragma unroll
        for (int j = 0; j < 3; ++j)
          acc[rt][j] = __builtin_amdgcn_mfma_f32_16x16x32_f16(af[rt], wf[j],
                                                              acc[rt][j], 0, 0, 0);
    }
    // epilogue: tanh + bias -> A3 (FRAG(384)); pad cols produce tanh(0)=0
#pragma unroll
    for (int j = 0; j < 3; ++j) {
      const int col = w * 48 + j * 16 + m;
      const float bv = b2[col];
      const int cb = (col >> 5) * 512 + ((col >> 3) & 3) * 128 + (col & 7);
#pragma unroll
      for (int rt = 0; rt < 2; ++rt)
#pragma unroll
        for (int r = 0; r < 4; ++r)
          A3s[rt * 6144 + cb + (q * 4 + r) * 8] = (half_t)ftanh_(acc[rt][j][r] + bv);
    }
  }
  __syncthreads();

  // ---- dec3: K=384, wave cols [w*64, w*64+64) -> logits f32 in LDS ----
  {
    float4v acc[2][4] = {};
    const half_t* w3 = W3f + (size_t)(w * 4) * 6144 + lane * 8;
#pragma unroll 2
    for (int c = 0; c < 12; ++c) {
      half8 wf[4], af[2];
#pragma unroll
      for (int j = 0; j < 4; ++j)
        wf[j] = *(const half8*)(w3 + j * 6144 + c * 512);
#pragma unroll
      for (int rt = 0; rt < 2; ++rt)
        af[rt] = *(const half8*)(A3s + rt * 6144 + c * 512 + q * 128 + m * 8);
#pragma unroll
      for (int rt = 0; rt < 2; ++rt)
#pragma unroll
        for (int j = 0; j < 4; ++j)
          acc[rt][j] = __builtin_amdgcn_mfma_f32_16x16x32_f16(af[rt], wf[j],
                                                              acc[rt][j], 0, 0, 0);
    }
    // LOGL aliases A1s: A1s dead since dec1 (2 barriers ago).
#pragma unroll
    for (int j = 0; j < 4; ++j) {
      const int col = w * 64 + j * 16 + m;
      const float bv = b3[col];
#pragma unroll
      for (int rt = 0; rt < 2; ++rt)
#pragma unroll
        for (int r = 0; r < 4; ++r)
          LOGL[(rt * 16 + q * 4 + r) * 512 + col] = acc[rt][j][r] + bv;
    }
  }
  __syncthreads();

  // ---- softmax over 512 cols: wave w handles rows w*4 .. w*4+3 ----
#pragma unroll
  for (int rr = 0; rr < 4; ++rr) {
    const int row = w * 4 + rr;
    const float4v* srcv = (const float4v*)(LOGL + row * 512);
    const float4v v0 = srcv[lane * 2];
    const float4v v1 = srcv[lane * 2 + 1];
    float mx = fmaxf(fmaxf(fmaxf(v0.x, v0.y), fmaxf(v0.z, v0.w)),
                     fmaxf(fmaxf(v1.x, v1.y), fmaxf(v1.z, v1.w)));
#pragma unroll
    for (int off = 32; off > 0; off >>= 1) mx = fmaxf(mx, __shfl_xor(mx, off, 64));
    const float e0 = __expf(v0.x - mx), e1 = __expf(v0.y - mx);
    const float e2 = __expf(v0.z - mx), e3 = __expf(v0.w - mx);
    const float e4 = __expf(v1.x - mx), e5 = __expf(v1.y - mx);
    const float e6 = __expf(v1.z - mx), e7 = __expf(v1.w - mx);
    float sum = ((e0 + e1) + (e2 + e3)) + ((e4 + e5) + (e6 + e7));
#pragma unroll
    for (int off = 32; off > 0; off >>= 1) sum += __shfl_xor(sum, off, 64);
    const float inv = 1.0f / sum;
    float4v o0, o1;
    o0.x = e0 * inv; o0.y = e1 * inv; o0.z = e2 * inv; o0.w = e3 * inv;
    o1.x = e4 * inv; o1.y = e5 * inv; o1.z = e6 * inv; o1.w = e7 * inv;
    float4v* dst = (float4v*)(out + ((size_t)b * 32 + row) * 512);
    dst[lane * 2] = o0;
    dst[lane * 2 + 1] = o1;
  }
}

// ---------------------------------------------------------------------------
// prep_pack: blocks [0,16384) -> XH f16 [8192,2048]; [16384,24576) -> WALL.
// ---------------------------------------------------------------------------
__global__ void prep_pack(const float* __restrict__ x, const float* __restrict__ h,
                          const float* __restrict__ Wfi, const float* __restrict__ Wfh,
                          const float* __restrict__ Wii, const float* __restrict__ Wih,
                          const float* __restrict__ Wsi, const float* __restrict__ Wsh,
                          const float* __restrict__ Woi, const float* __restrict__ Woh,
                          half_t* __restrict__ xh, half_t* __restrict__ wall) {
  const int bid = blockIdx.x;
  const float* src;
  half_t* dst;
  size_t idx;
  if (bid < 16384) {
    idx = ((size_t)bid * 256 + threadIdx.x) * 4;
    const size_t bb = idx >> 11;
    const int col = (int)(idx & 2047);
    src = (col < 1024) ? (x + bb * 1024 + col) : (h + bb * 1024 + (col - 1024));
    dst = xh + idx;
  } else {
    idx = ((size_t)(bid - 16384) * 256 + threadIdx.x) * 4;
    const int n = (int)(idx >> 11);
    const int col = (int)(idx & 2047);
    const int g = (n >> 4) & 3;
    const size_t u = (size_t)(((n >> 6) << 4) | (n & 15));
    const float* Wi = (g == 0) ? Wfi : (g == 1) ? Wii : (g == 2) ? Wsi : Woi;
    const float* Wh = (g == 0) ? Wfh : (g == 1) ? Wih : (g == 2) ? Wsh : Woh;
    src = (col < 1024) ? (Wi + u * 1024 + col) : (Wh + u * 1024 + (col - 1024));
    dst = wall + idx;
  }
  const float4v v = *(const float4v*)src;
  half4v o;
  o.x = (half_t)v.x; o.y = (half_t)v.y; o.z = (half_t)v.z; o.w = (half_t)v.w;
  *(half4v*)dst = o;
}

// ---------------------------------------------------------------------------
// prep_small: decoder weights -> B-FRAG order (f16), biases.
// BFRAG(K) addr(col,k) = (col>>4)*16K + (k>>5)*512 + ((k>>3)&3)*128
//                        + (col&15)*8 + (k&7)   [halves]
// WD1 [0,512) | WD2 [512,704) | WD3 [704,896) | BALL [896,912) | BD2 [912,914)
// ---------------------------------------------------------------------------
__global__ void prep_small(const float* __restrict__ Wd1, const float* __restrict__ Wd2,
                           const float* __restrict__ Wd3, const float* __restrict__ bd2,
                           const float* __restrict__ bfi, const float* __restrict__ bfh,
                           const float* __restrict__ bii, const float* __restrict__ bih,
                           const float* __restrict__ bsi, const float* __restrict__ bsh,
                           const float* __restrict__ boi, const float* __restrict__ boh,
                           half_t* __restrict__ WD1, half_t* __restrict__ WD2h,
                           half_t* __restrict__ WD3h, float* __restrict__ BALL,
                           float* __restrict__ BD2) {
  const int bid = blockIdx.x;
  const int tid = threadIdx.x;
  if (bid < 512) {
    // WD1: 512x1024 -> BFRAG(1024)
    const size_t i4 = ((size_t)bid * 256 + tid) * 4;
    const int col = (int)(i4 >> 10);
    const int k0 = (int)(i4 & 1023);
    const float4v v = *(const float4v*)(Wd1 + i4);
    half4v o;
    o.x = (half_t)v.x; o.y = (half_t)v.y; o.z = (half_t)v.z; o.w = (half_t)v.w;
    const size_t fa = (size_t)(col >> 4) * 16384 + (k0 >> 5) * 512 +
                      ((k0 >> 3) & 3) * 128 + (col & 15) * 8 + (k0 & 7);
    *(half4v*)(WD1 + fa) = o;
  } else if (bid < 704) {
    // WD2: 384x512 (rows>=341 zero) -> BFRAG(512)
    const size_t i4 = ((size_t)(bid - 512) * 256 + tid) * 4;
    const int col = (int)(i4 >> 9);
    const int k0 = (int)(i4 & 511);
    half4v o;
    if (col < 341) {
      const float4v v = *(const float4v*)(Wd2 + (size_t)col * 512 + k0);
      o.x = (half_t)v.x; o.y = (half_t)v.y; o.z = (half_t)v.z; o.w = (half_t)v.w;
    } else {
      o.x = (half_t)0.f; o.y = (half_t)0.f; o.z = (half_t)0.f; o.w = (half_t)0.f;
    }
    const size_t fa = (size_t)(col >> 4) * 8192 + (k0 >> 5) * 512 +
                      ((k0 >> 3) & 3) * 128 + (col & 15) * 8 + (k0 & 7);
    *(half4v*)(WD2h + fa) = o;
  } else if (bid < 896) {
    // WD3: 512x384 (k>=341 zero) -> BFRAG(384)
    const size_t i4 = ((size_t)(bid - 704) * 256 + tid) * 4;
    const int col = (int)(i4 / 384);
    const int k0 = (int)(i4 - (size_t)col * 384);
    half4v o;
    o.x = (k0 + 0 < 341) ? (half_t)Wd3[(size_t)col * 341 + k0 + 0] : (half_t)0.f;
    o.y = (k0 + 1 < 341) ? (half_t)Wd3[(size_t)col * 341 + k0 + 1] : (half_t)0.f;
    o.z = (k0 + 2 < 341) ? (half_t)Wd3[(size_t)col * 341 + k0 + 2] : (half_t)0.f;
    o.w = (k0 + 3 < 341) ? (half_t)Wd3[(size_t)col * 341 + k0 + 3] : (half_t)0.f;
    const size_t fa = (size_t)(col >> 4) * 6144 + (k0 >> 5) * 512 +
                      ((k0 >> 3) & 3) * 128 + (col & 15) * 8 + (k0 & 7);
    *(half4v*)(WD3h + fa) = o;
  } else if (bid < 912) {
    const int n = (bid - 896) * 256 + tid;
    const int g = (n >> 4) & 3;
    const int u = ((n >> 6) << 4) | (n & 15);
    const float* bi = (g == 0) ? bfi : (g == 1) ? bii : (g == 2) ? bsi : boi;
    const float* bh = (g == 0) ? bfh : (g == 1) ? bih : (g == 2) ? bsh : boh;
    BALL[n] = bi[u] + bh[u];
  } else {
    const int i = (bid - 912) * 256 + tid;
    if (i < 384) BD2[i] = (i < 341) ? bd2[i] : 0.0f;
  }
}

// ---------------------------------------------------------------------------
extern "C" void kernel_launch(void* const* d_in, const int* in_sizes, int n_in,
                              void* d_out, int out_size, void* d_ws, size_t ws_size,
                              hipStream_t stream) {
  const float* x = (const float*)d_in[0];
  const float* h = (const float*)d_in[1];
  const float* c = (const float*)d_in[2];
  const float* Wfi = (const float*)d_in[3];  const float* bfi = (const float*)d_in[4];
  const float* Wfh = (const float*)d_in[5];  const float* bfh = (const float*)d_in[6];
  const float* Wii = (const float*)d_in[7];  const float* bii = (const float*)d_in[8];
  const float* Wih = (const float*)d_in[9];  const float* bih = (const float*)d_in[10];
  const float* Wsi = (const float*)d_in[11]; const float* bsi = (const float*)d_in[12];
  const float* Wsh = (const float*)d_in[13]; const float* bsh = (const float*)d_in[14];
  const float* Woi = (const float*)d_in[15]; const float* boi = (const float*)d_in[16];
  const float* Woh = (const float*)d_in[17]; const float* boh = (const float*)d_in[18];
  const float* Wd1 = (const float*)d_in[19]; const float* bd1 = (const float*)d_in[20];
  const float* Wd2 = (const float*)d_in[21]; const float* bd2 = (const float*)d_in[22];
  const float* Wd3 = (const float*)d_in[23]; const float* bd3 = (const float*)d_in[24];

  char* ws = (char*)d_ws;
  size_t o = 0;
  auto alloc = [&](size_t bytes) {
    size_t cur = o;
    o += (bytes + 255) & ~(size_t)255;
    return cur;
  };
  half_t* XH   = (half_t*)(ws + alloc((size_t)8192 * 2048 * 2));  // 33.5 MB
  half_t* WALL = (half_t*)(ws + alloc((size_t)4096 * 2048 * 2));  // 16.8 MB
  float*  BALL = (float*)(ws + alloc(4096 * 4));
  half_t* WD1  = (half_t*)(ws + alloc((size_t)512 * 1024 * 2));   // BFRAG(1024)
  half_t* WD2  = (half_t*)(ws + alloc((size_t)384 * 512 * 2));    // BFRAG(512)
  float*  BD2  = (float*)(ws + alloc(384 * 4));
  half_t* WD3  = (half_t*)(ws + alloc((size_t)512 * 384 * 2));    // BFRAG(384)
  half_t* H2F  = (half_t*)(ws + alloc((size_t)8192 * 1024 * 2));  // 16.8 MB frag

  float* h_out = (float*)d_out;                          // [8192,1024] f32
  float* d_outp = (float*)d_out + (size_t)8192 * 1024;   // [8192,512] f32

  // prep: 2 launches (inputs re-poisoned every call, so convert every call)
  prep_pack<<<24576, 256, 0, stream>>>(x, h, Wfi, Wfh, Wii, Wih, Wsi, Wsh, Woi, Woh,
                                       XH, WALL);
  prep_small<<<914, 256, 0, stream>>>(Wd1, Wd2, Wd3, bd2, bfi, bfh, bii, bih, bsi, bsh,
                                      boi, boh, WD1, WD2, WD3, BALL, BD2);

  // gates GEMM + fused LSTM -> h_out (f32) + H2F (f16 frag order)
  gemm_gates<<<512, 512, 0, stream>>>(XH, WALL, BALL, c, h_out, H2F);

  // fused decoder: dec1+dec2+dec3+softmax, one launch, 1 block/CU
  fused_decoder<<<256, 512, 0, stream>>>(H2F, WD1, bd1, WD2, BD2, WD3, bd3, d_outp);
}

// Round 9
// 381.508 us; speedup vs baseline: 1.0176x; 1.0176x over previous
//
#include <hip/hip_runtime.h>
#include <cstdint>
#include <cstddef>

// ---------------------------------------------------------------------------
// LSTM cell + 3-layer decoder, MI355X (gfx950)
// B=8192, H=1024, D_IN=1024, D1=512, D2=341(pad 384), A=512
// R14: restore best-known config. Gates = EXACT R7 (BK=32, 256x256, 3-buf,
// counted vmcnt(4), 2 phases/tile with 4 barriers AND the lgkmcnt(0)+
// sched_barrier pins — R13 proved removing them costs 30us; all four
// structural deviations from R7 regressed, so R7 is frozen verbatim).
// fused_decoder = R9 form. prep_small merged INTO prep_pack (one prep_all
// launch, 25490 blocks) to cut one launch gap; bodies unchanged.
// FRAG(K) addr(row,k) = (row>>4)*16K + (k>>5)*512 + ((k>>3)&3)*128
//                       + (row&15)*8 + (k&7)   [halves]
// ---------------------------------------------------------------------------

typedef _Float16 half_t;
typedef _Float16 half8 __attribute__((ext_vector_type(8)));
typedef _Float16 half4v __attribute__((ext_vector_type(4)));
typedef float float4v __attribute__((ext_vector_type(4)));

#define GLD_LDS16(gptr, lptr)                                                  \
  __builtin_amdgcn_global_load_lds(                                            \
      (const __attribute__((address_space(1))) void*)(gptr),                   \
      (__attribute__((address_space(3))) void*)(lptr), 16, 0, 0)

__device__ __forceinline__ float fsig(float x) {
  return 1.0f / (1.0f + __expf(-x));
}
__device__ __forceinline__ float ftanh_(float x) {
  const float e = __expf(2.0f * x);
  return 1.0f - 2.0f / (e + 1.0f);
}

// ---------------------------------------------------------------------------
// Gates GEMM with fused LSTM epilogue. (R7 structure, measured 171.5us.
// FROZEN — do not deviate: R8/R11/R12/R13 all regressed.)
// 256x256 tile, BK=32, 512 threads (8 waves, 2M x 4N of 128x64 each).
// LDS: 3 buffers x (A 16KB + B 16KB) = 96 KB. Prefetch distance 2 K-tiles;
// counted vmcnt(4); 2 phases/K-tile with 4 barriers (fine interleave).
// Writes h_out (f32 row-major) and H2F (f16, FRAG(1024) order).
// ---------------------------------------------------------------------------
__global__ __launch_bounds__(512, 2) void gemm_gates(const half_t* __restrict__ A,
                                                     const half_t* __restrict__ Bw,
                                                     const float* __restrict__ bias,
                                                     const float* __restrict__ cin,
                                                     float* __restrict__ hout,
                                                     half_t* __restrict__ h2f) {
  constexpr int K = 2048;
  constexpr int NT = 64;  // K / 32
  __shared__ alignas(16) half_t As[3][256 * 32];
  __shared__ alignas(16) half_t Bs[3][256 * 32];
  const int tid = threadIdx.x;
  const int lane = tid & 63;
  const int wave = tid >> 6;
  const int m = lane & 15;
  const int q = lane >> 4;
  const int ks = (q ^ ((m >> 1) & 3)) << 3;  // swizzled k-chunk (halves)
  const int wm = (wave >> 2) << 7;           // 0 / 128
  const int wn = (wave & 3) << 6;            // 0 / 64 / 128 / 192

  const int bid = blockIdx.x;
  const int xcd = bid & 7;
  const int l = bid >> 3;  // 0..63
  const size_t tile_n = (size_t)((xcd << 1) | (l & 1)) << 8;
  const size_t tile_m = (size_t)(l >> 1) << 8;

  const int ci0 = tid, ci1 = tid + 512;
  const int r0 = ci0 >> 2, k0s = (ci0 & 3) ^ ((r0 >> 1) & 3);
  const int r1 = ci1 >> 2, k1s = (ci1 & 3) ^ ((r1 >> 1) & 3);
  const half_t* Ag0 = A + (tile_m + r0) * (size_t)K + k0s * 8;
  const half_t* Ag1 = A + (tile_m + r1) * (size_t)K + k1s * 8;
  const half_t* Bg0 = Bw + (tile_n + r0) * (size_t)K + k0s * 8;
  const half_t* Bg1 = Bw + (tile_n + r1) * (size_t)K + k1s * 8;
  const int p0 = ci0 * 16, p1 = ci1 * 16;

  // prologue: stage K-tiles 0 and 1; wait only for tile 0 (vmcnt(4)).
  GLD_LDS16(Ag0, (char*)As[0] + p0);
  GLD_LDS16(Ag1, (char*)As[0] + p1);
  GLD_LDS16(Bg0, (char*)Bs[0] + p0);
  GLD_LDS16(Bg1, (char*)Bs[0] + p1);
  GLD_LDS16(Ag0 + 32, (char*)As[1] + p0);
  GLD_LDS16(Ag1 + 32, (char*)As[1] + p1);
  GLD_LDS16(Bg0 + 32, (char*)Bs[1] + p0);
  GLD_LDS16(Bg1 + 32, (char*)Bs[1] + p1);
  asm volatile("s_waitcnt vmcnt(4)" ::: "memory");
  __builtin_amdgcn_s_barrier();
  __builtin_amdgcn_sched_barrier(0);

  float4v acc[8][4] = {};
  int bc = 0;  // buffer of current K-tile
  for (int t = 0; t < NT; ++t) {
    const half_t* as = As[bc];
    const half_t* bs = Bs[bc];
    const int bst = (bc + 2 >= 3) ? bc - 1 : bc + 2;  // (bc+2)%3
    const size_t koff = (size_t)(t + 2) * 32;
    half8 af[4], bf[4];
    // ---- phase 0: rows [wm, wm+64) x all 4 n-frags ----
#pragma unroll
    for (int i = 0; i < 4; ++i)
      af[i] = *(const half8*)(as + (wm + i * 16 + m) * 32 + ks);
#pragma unroll
    for (int j = 0; j < 4; ++j)
      bf[j] = *(const half8*)(bs + (wn + j * 16 + m) * 32 + ks);
    if (t < NT - 2) {
      GLD_LDS16(Ag0 + koff, (char*)As[bst] + p0);
      GLD_LDS16(Ag1 + koff, (char*)As[bst] + p1);
    }
    __builtin_amdgcn_s_barrier();
    asm volatile("s_waitcnt lgkmcnt(0)" ::: "memory");
    __builtin_amdgcn_sched_barrier(0);  // rule 18: pin MFMA below the wait
    __builtin_amdgcn_s_setprio(1);
#pragma unroll
    for (int i = 0; i < 4; ++i)
#pragma unroll
      for (int j = 0; j < 4; ++j)
        acc[i][j] = __builtin_amdgcn_mfma_f32_16x16x32_f16(af[i], bf[j],
                                                           acc[i][j], 0, 0, 0);
    __builtin_amdgcn_s_setprio(0);
    __builtin_amdgcn_s_barrier();
    __builtin_amdgcn_sched_barrier(0);
    // ---- phase 1: rows [wm+64, wm+128) x all 4 n-frags (bf reused) ----
    half8 ag[4];
#pragma unroll
    for (int i = 0; i < 4; ++i)
      ag[i] = *(const half8*)(as + (wm + 64 + i * 16 + m) * 32 + ks);
    if (t < NT - 2) {
      GLD_LDS16(Bg0 + koff, (char*)Bs[bst] + p0);
      GLD_LDS16(Bg1 + koff, (char*)Bs[bst] + p1);
    }
    __builtin_amdgcn_s_barrier();
    asm volatile("s_waitcnt lgkmcnt(0)" ::: "memory");
    __builtin_amdgcn_sched_barrier(0);
    __builtin_amdgcn_s_setprio(1);
#pragma unroll
    for (int i = 0; i < 4; ++i)
#pragma unroll
      for (int j = 0; j < 4; ++j)
        acc[4 + i][j] = __builtin_amdgcn_mfma_f32_16x16x32_f16(
            ag[i], bf[j], acc[4 + i][j], 0, 0, 0);
    __builtin_amdgcn_s_setprio(0);
    // counted per-tile wait: tile t+1 landed, tile t+2 stays in flight.
    if (t < NT - 2) {
      asm volatile("s_waitcnt vmcnt(4)" ::: "memory");
    } else if (t == NT - 2) {
      asm volatile("s_waitcnt vmcnt(0)" ::: "memory");
    }
    __builtin_amdgcn_s_barrier();
    __builtin_amdgcn_sched_barrier(0);
    bc = (bc + 1 == 3) ? 0 : bc + 1;
  }

  // fused LSTM epilogue (C/D: col=lane&15, row=q*4+reg [m89])
  const int nwave = (int)tile_n + wn;
  const int u = ((nwave >> 6) << 4) + m;  // hidden unit index
  const int rtb = (int)((tile_m + wm) >> 4);
  const int ubase = (u >> 5) * 512 + ((u >> 3) & 3) * 128 + (u & 7);
  float bg[4];
#pragma unroll
  for (int g = 0; g < 4; ++g) bg[g] = bias[nwave + g * 16 + m];
#pragma unroll
  for (int i = 0; i < 8; ++i) {
#pragma unroll
    for (int r = 0; r < 4; ++r) {
      const size_t row = tile_m + wm + q * 4 + i * 16 + r;
      const size_t off = row * 1024 + u;
      const float F = fsig(acc[i][0][r] + bg[0]);
      const float I = fsig(acc[i][1][r] + bg[1]);
      const float S = ftanh_(acc[i][2][r] + bg[2]);
      const float O = fsig(acc[i][3][r] + bg[3]);
      const float cn = cin[off] * F + I * S;
      const float hn = O * ftanh_(cn);
      hout[off] = hn;
      h2f[(size_t)(rtb + i) * 16384 + ubase + (q * 4 + r) * 8] = (half_t)hn;
    }
  }
}

// ---------------------------------------------------------------------------
// Fused decoder (R9 form): dec1(1024->512,tanh) + dec2(512->384,tanh) +
// dec3(384->512) + softmax. 32 batch rows per block, 256 blocks (1/CU).
// Activations in LDS: A1 64KB -> A2 32KB -> A3 24KB; logits alias A1.
// Weights pre-packed B-FRAG -> coalesced 1KB wave reads.
// ---------------------------------------------------------------------------
__global__ __launch_bounds__(512, 2) void fused_decoder(
    const half_t* __restrict__ h2f,  // FRAG(1024), 512 row-tiles
    const half_t* __restrict__ W1f,  // BFRAG(1024): 32 col-tiles x 16384
    const float* __restrict__ b1,    // [512]
    const half_t* __restrict__ W2f,  // BFRAG(512):  24 col-tiles x 8192
    const float* __restrict__ b2,    // [384] (padded, zeros past 341)
    const half_t* __restrict__ W3f,  // BFRAG(384):  32 col-tiles x 6144
    const float* __restrict__ b3,    // [512]
    float* __restrict__ out) {       // [8192][512] f32
  __shared__ alignas(16) half_t A1s[2 * 16384];  // 64KB (aliased by logits)
  __shared__ alignas(16) half_t A2s[2 * 8192];   // 32KB
  __shared__ alignas(16) half_t A3s[2 * 6144];   // 24KB
  float* LOGL = (float*)A1s;                     // [32][512] f32

  const int tid = threadIdx.x;
  const int lane = tid & 63;
  const int w = tid >> 6;  // wave 0..7
  const int m = lane & 15;
  const int q = lane >> 4;
  const int b = blockIdx.x;  // rows b*32 .. b*32+31 (row-tiles 2b, 2b+1)

  // ---- stage A1: 64KB contiguous from H2F (FRAG order preserved) ----
  const half_t* src = h2f + (size_t)b * 32768;
#pragma unroll
  for (int it = 0; it < 8; ++it)
    GLD_LDS16(src + (it * 512 + tid) * 8, (char*)A1s + (it * 512 + tid) * 16);
  asm volatile("s_waitcnt vmcnt(0)" ::: "memory");
  __syncthreads();

  // ---- dec1: K=1024, wave cols [w*64, w*64+64) ----
  {
    float4v acc[2][4] = {};
    const half_t* w1 = W1f + (size_t)(w * 4) * 16384 + lane * 8;
#pragma unroll 2
    for (int c = 0; c < 32; ++c) {
      half8 wf[4], af[2];
#pragma unroll
      for (int j = 0; j < 4; ++j)
        wf[j] = *(const half8*)(w1 + j * 16384 + c * 512);
#pragma unroll
      for (int rt = 0; rt < 2; ++rt)
        af[rt] = *(const half8*)(A1s + rt * 16384 + c * 512 + q * 128 + m * 8);
#pragma unroll
      for (int rt = 0; rt < 2; ++rt)
#pragma unroll
        for (int j = 0; j < 4; ++j)
          acc[rt][j] = __builtin_amdgcn_mfma_f32_16x16x32_f16(af[rt], wf[j],
                                                              acc[rt][j], 0, 0, 0);
    }
    // epilogue: tanh + bias -> A2 (FRAG(512))
#pragma unroll
    for (int j = 0; j < 4; ++j) {
      const int col = w * 64 + j * 16 + m;
      const float bv = b1[col];
      const int cb = (col >> 5) * 512 + ((col >> 3) & 3) * 128 + (col & 7);
#pragma unroll
      for (int rt = 0; rt < 2; ++rt)
#pragma unroll
        for (int r = 0; r < 4; ++r)
          A2s[rt * 8192 + cb + (q * 4 + r) * 8] = (half_t)ftanh_(acc[rt][j][r] + bv);
    }
  }
  __syncthreads();

  // ---- dec2: K=512, wave cols [w*48, w*48+48) ----
  {
    float4v acc[2][3] = {};
    const half_t* w2 = W2f + (size_t)(w * 3) * 8192 + lane * 8;
#pragma unroll 2
    for (int c = 0; c < 16; ++c) {
      half8 wf[3], af[2];
#pragma unroll
      for (int j = 0; j < 3; ++j)
        wf[j] = *(const half8*)(w2 + j * 8192 + c * 512);
#pragma unroll
      for (int rt = 0; rt < 2; ++rt)
        af[rt] = *(const half8*)(A2s + rt * 8192 + c * 512 + q * 128 + m * 8);
#pragma unroll
      for (int rt = 0; rt < 2; ++rt)
#pragma unroll
        for (int j = 0; j < 3; ++j)
          acc[rt][j] = __builtin_amdgcn_mfma_f32_16x16x32_f16(af[rt], wf[j],
                                                              acc[rt][j], 0, 0, 0);
    }
    // epilogue: tanh + bias -> A3 (FRAG(384)); pad cols produce tanh(0)=0
#pragma unroll
    for (int j = 0; j < 3; ++j) {
      const int col = w * 48 + j * 16 + m;
      const float bv = b2[col];
      const int cb = (col >> 5) * 512 + ((col >> 3) & 3) * 128 + (col & 7);
#pragma unroll
      for (int rt = 0; rt < 2; ++rt)
#pragma unroll
        for (int r = 0; r < 4; ++r)
          A3s[rt * 6144 + cb + (q * 4 + r) * 8] = (half_t)ftanh_(acc[rt][j][r] + bv);
    }
  }
  __syncthreads();

  // ---- dec3: K=384, wave cols [w*64, w*64+64) -> logits f32 in LDS ----
  {
    float4v acc[2][4] = {};
    const half_t* w3 = W3f + (size_t)(w * 4) * 6144 + lane * 8;
#pragma unroll 2
    for (int c = 0; c < 12; ++c) {
      half8 wf[4], af[2];
#pragma unroll
      for (int j = 0; j < 4; ++j)
        wf[j] = *(const half8*)(w3 + j * 6144 + c * 512);
#pragma unroll
      for (int rt = 0; rt < 2; ++rt)
        af[rt] = *(const half8*)(A3s + rt * 6144 + c * 512 + q * 128 + m * 8);
#pragma unroll
      for (int rt = 0; rt < 2; ++rt)
#pragma unroll
        for (int j = 0; j < 4; ++j)
          acc[rt][j] = __builtin_amdgcn_mfma_f32_16x16x32_f16(af[rt], wf[j],
                                                              acc[rt][j], 0, 0, 0);
    }
    // LOGL aliases A1s: A1s dead since dec1 (2 barriers ago).
#pragma unroll
    for (int j = 0; j < 4; ++j) {
      const int col = w * 64 + j * 16 + m;
      const float bv = b3[col];
#pragma unroll
      for (int rt = 0; rt < 2; ++rt)
#pragma unroll
        for (int r = 0; r < 4; ++r)
          LOGL[(rt * 16 + q * 4 + r) * 512 + col] = acc[rt][j][r] + bv;
    }
  }
  __syncthreads();

  // ---- softmax over 512 cols: wave w handles rows w*4 .. w*4+3 ----
#pragma unroll
  for (int rr = 0; rr < 4; ++rr) {
    const int row = w * 4 + rr;
    const float4v* srcv = (const float4v*)(LOGL + row * 512);
    const float4v v0 = srcv[lane * 2];
    const float4v v1 = srcv[lane * 2 + 1];
    float mx = fmaxf(fmaxf(fmaxf(v0.x, v0.y), fmaxf(v0.z, v0.w)),
                     fmaxf(fmaxf(v1.x, v1.y), fmaxf(v1.z, v1.w)));
#pragma unroll
    for (int off = 32; off > 0; off >>= 1) mx = fmaxf(mx, __shfl_xor(mx, off, 64));
    const float e0 = __expf(v0.x - mx), e1 = __expf(v0.y - mx);
    const float e2 = __expf(v0.z - mx), e3 = __expf(v0.w - mx);
    const float e4 = __expf(v1.x - mx), e5 = __expf(v1.y - mx);
    const float e6 = __expf(v1.z - mx), e7 = __expf(v1.w - mx);
    float sum = ((e0 + e1) + (e2 + e3)) + ((e4 + e5) + (e6 + e7));
#pragma unroll
    for (int off = 32; off > 0; off >>= 1) sum += __shfl_xor(sum, off, 64);
    const float inv = 1.0f / sum;
    float4v o0, o1;
    o0.x = e0 * inv; o0.y = e1 * inv; o0.z = e2 * inv; o0.w = e3 * inv;
    o1.x = e4 * inv; o1.y = e5 * inv; o1.z = e6 * inv; o1.w = e7 * inv;
    float4v* dst = (float4v*)(out + ((size_t)b * 32 + row) * 512);
    dst[lane * 2] = o0;
    dst[lane * 2 + 1] = o1;
  }
}

// ---------------------------------------------------------------------------
// prep_all: single prep launch (prep_pack + prep_small merged; bodies
// unchanged, block ranges offset).
// blocks [0,16384)      -> XH f16 [8192,2048]
// blocks [16384,24576)  -> WALL f16 (gate weights interleaved)
// blocks [24576,25490)  -> decoder weights B-FRAG + biases
// BFRAG(K) addr(col,k) = (col>>4)*16K + (k>>5)*512 + ((k>>3)&3)*128
//                        + (col&15)*8 + (k&7)   [halves]
// ---------------------------------------------------------------------------
__global__ void prep_all(const float* __restrict__ x, const float* __restrict__ h,
                         const float* __restrict__ Wfi, const float* __restrict__ Wfh,
                         const float* __restrict__ Wii, const float* __restrict__ Wih,
                         const float* __restrict__ Wsi, const float* __restrict__ Wsh,
                         const float* __restrict__ Woi, const float* __restrict__ Woh,
                         const float* __restrict__ Wd1, const float* __restrict__ Wd2,
                         const float* __restrict__ Wd3, const float* __restrict__ bd2,
                         const float* __restrict__ bfi, const float* __restrict__ bfh,
                         const float* __restrict__ bii, const float* __restrict__ bih,
                         const float* __restrict__ bsi, const float* __restrict__ bsh,
                         const float* __restrict__ boi, const float* __restrict__ boh,
                         half_t* __restrict__ xh, half_t* __restrict__ wall,
                         half_t* __restrict__ WD1, half_t* __restrict__ WD2h,
                         half_t* __restrict__ WD3h, float* __restrict__ BALL,
                         float* __restrict__ BD2) {
  const int bid = blockIdx.x;
  const int tid = threadIdx.x;
  if (bid < 24576) {
    const float* src;
    half_t* dst;
    size_t idx;
    if (bid < 16384) {
      idx = ((size_t)bid * 256 + tid) * 4;
      const size_t bb = idx >> 11;
      const int col = (int)(idx & 2047);
      src = (col < 1024) ? (x + bb * 1024 + col) : (h + bb * 1024 + (col - 1024));
      dst = xh + idx;
    } else {
      idx = ((size_t)(bid - 16384) * 256 + tid) * 4;
      const int n = (int)(idx >> 11);
      const int col = (int)(idx & 2047);
      const int g = (n >> 4) & 3;
      const size_t u = (size_t)(((n >> 6) << 4) | (n & 15));
      const float* Wi = (g == 0) ? Wfi : (g == 1) ? Wii : (g == 2) ? Wsi : Woi;
      const float* Wh = (g == 0) ? Wfh : (g == 1) ? Wih : (g == 2) ? Wsh : Woh;
      src = (col < 1024) ? (Wi + u * 1024 + col) : (Wh + u * 1024 + (col - 1024));
      dst = wall + idx;
    }
    const float4v v = *(const float4v*)src;
    half4v o;
    o.x = (half_t)v.x; o.y = (half_t)v.y; o.z = (half_t)v.z; o.w = (half_t)v.w;
    *(half4v*)dst = o;
    return;
  }
  const int b2i = bid - 24576;  // 0..913
  if (b2i < 512) {
    // WD1: 512x1024 -> BFRAG(1024)
    const size_t i4 = ((size_t)b2i * 256 + tid) * 4;
    const int col = (int)(i4 >> 10);
    const int k0 = (int)(i4 & 1023);
    const float4v v = *(const float4v*)(Wd1 + i4);
    half4v o;
    o.x = (half_t)v.x; o.y = (half_t)v.y; o.z = (half_t)v.z; o.w = (half_t)v.w;
    const size_t fa = (size_t)(col >> 4) * 16384 + (k0 >> 5) * 512 +
                      ((k0 >> 3) & 3) * 128 + (col & 15) * 8 + (k0 & 7);
    *(half4v*)(WD1 + fa) = o;
  } else if (b2i < 704) {
    // WD2: 384x512 (rows>=341 zero) -> BFRAG(512)
    const size_t i4 = ((size_t)(b2i - 512) * 256 + tid) * 4;
    const int col = (int)(i4 >> 9);
    const int k0 = (int)(i4 & 511);
    half4v o;
    if (col < 341) {
      const float4v v = *(const float4v*)(Wd2 + (size_t)col * 512 + k0);
      o.x = (half_t)v.x; o.y = (half_t)v.y; o.z = (half_t)v.z; o.w = (half_t)v.w;
    } else {
      o.x = (half_t)0.f; o.y = (half_t)0.f; o.z = (half_t)0.f; o.w = (half_t)0.f;
    }
    const size_t fa = (size_t)(col >> 4) * 8192 + (k0 >> 5) * 512 +
                      ((k0 >> 3) & 3) * 128 + (col & 15) * 8 + (k0 & 7);
    *(half4v*)(WD2h + fa) = o;
  } else if (b2i < 896) {
    // WD3: 512x384 (k>=341 zero) -> BFRAG(384)
    const size_t i4 = ((size_t)(b2i - 704) * 256 + tid) * 4;
    const int col = (int)(i4 / 384);
    const int k0 = (int)(i4 - (size_t)col * 384);
    half4v o;
    o.x = (k0 + 0 < 341) ? (half_t)Wd3[(size_t)col * 341 + k0 + 0] : (half_t)0.f;
    o.y = (k0 + 1 < 341) ? (half_t)Wd3[(size_t)col * 341 + k0 + 1] : (half_t)0.f;
    o.z = (k0 + 2 < 341) ? (half_t)Wd3[(size_t)col * 341 + k0 + 2] : (half_t)0.f;
    o.w = (k0 + 3 < 341) ? (half_t)Wd3[(size_t)col * 341 + k0 + 3] : (half_t)0.f;
    const size_t fa = (size_t)(col >> 4) * 6144 + (k0 >> 5) * 512 +
                      ((k0 >> 3) & 3) * 128 + (col & 15) * 8 + (k0 & 7);
    *(half4v*)(WD3h + fa) = o;
  } else if (b2i < 912) {
    const int n = (b2i - 896) * 256 + tid;
    const int g = (n >> 4) & 3;
    const int u = ((n >> 6) << 4) | (n & 15);
    const float* bi = (g == 0) ? bfi : (g == 1) ? bii : (g == 2) ? bsi : boi;
    const float* bh = (g == 0) ? bfh : (g == 1) ? bih : (g == 2) ? bsh : boh;
    BALL[n] = bi[u] + bh[u];
  } else {
    const int i = (b2i - 912) * 256 + tid;
    if (i < 384) BD2[i] = (i < 341) ? bd2[i] : 0.0f;
  }
}

// ---------------------------------------------------------------------------
extern "C" void kernel_launch(void* const* d_in, const int* in_sizes, int n_in,
                              void* d_out, int out_size, void* d_ws, size_t ws_size,
                              hipStream_t stream) {
  const float* x = (const float*)d_in[0];
  const float* h = (const float*)d_in[1];
  const float* c = (const float*)d_in[2];
  const float* Wfi = (const float*)d_in[3];  const float* bfi = (const float*)d_in[4];
  const float* Wfh = (const float*)d_in[5];  const float* bfh = (const float*)d_in[6];
  const float* Wii = (const float*)d_in[7];  const float* bii = (const float*)d_in[8];
  const float* Wih = (const float*)d_in[9];  const float* bih = (const float*)d_in[10];
  const float* Wsi = (const float*)d_in[11]; const float* bsi = (const float*)d_in[12];
  const float* Wsh = (const float*)d_in[13]; const float* bsh = (const float*)d_in[14];
  const float* Woi = (const float*)d_in[15]; const float* boi = (const float*)d_in[16];
  const float* Woh = (const float*)d_in[17]; const float* boh = (const float*)d_in[18];
  const float* Wd1 = (const float*)d_in[19]; const float* bd1 = (const float*)d_in[20];
  const float* Wd2 = (const float*)d_in[21]; const float* bd2 = (const float*)d_in[22];
  const float* Wd3 = (const float*)d_in[23]; const float* bd3 = (const float*)d_in[24];

  char* ws = (char*)d_ws;
  size_t o = 0;
  auto alloc = [&](size_t bytes) {
    size_t cur = o;
    o += (bytes + 255) & ~(size_t)255;
    return cur;
  };
  half_t* XH   = (half_t*)(ws + alloc((size_t)8192 * 2048 * 2));  // 33.5 MB
  half_t* WALL = (half_t*)(ws + alloc((size_t)4096 * 2048 * 2));  // 16.8 MB
  float*  BALL = (float*)(ws + alloc(4096 * 4));
  half_t* WD1  = (half_t*)(ws + alloc((size_t)512 * 1024 * 2));   // BFRAG(1024)
  half_t* WD2  = (half_t*)(ws + alloc((size_t)384 * 512 * 2));    // BFRAG(512)
  float*  BD2  = (float*)(ws + alloc(384 * 4));
  half_t* WD3  = (half_t*)(ws + alloc((size_t)512 * 384 * 2));    // BFRAG(384)
  half_t* H2F  = (half_t*)(ws + alloc((size_t)8192 * 1024 * 2));  // 16.8 MB frag

  float* h_out = (float*)d_out;                          // [8192,1024] f32
  float* d_outp = (float*)d_out + (size_t)8192 * 1024;   // [8192,512] f32

  // single prep launch (inputs re-poisoned every call, so convert every call)
  prep_all<<<25490, 256, 0, stream>>>(x, h, Wfi, Wfh, Wii, Wih, Wsi, Wsh, Woi, Woh,
                                      Wd1, Wd2, Wd3, bd2, bfi, bfh, bii, bih, bsi,
                                      bsh, boi, boh, XH, WALL, WD1, WD2, WD3, BALL,
                                      BD2);

  // gates GEMM + fused LSTM -> h_out (f32) + H2F (f16 frag order)
  gemm_gates<<<512, 512, 0, stream>>>(XH, WALL, BALL, c, h_out, H2F);

  // fused decoder: dec1+dec2+dec3+softmax, one launch, 1 block/CU
  fused_decoder<<<256, 512, 0, stream>>>(H2F, WD1, bd1, WD2, BD2, WD3, bd3, d_outp);
}

// Round 10
// 377.265 us; speedup vs baseline: 1.0290x; 1.0112x over previous
//
#include <hip/hip_runtime.h>
#include <cstdint>
#include <cstddef>

// ---------------------------------------------------------------------------
// LSTM cell + 3-layer decoder, MI355X (gfx950)
// B=8192, H=1024, D_IN=1024, D1=512, D2=341(pad 384), A=512
// R15: R14 frozen (gates = exact R7, 170.6us measured; prep_all merged;
// fused_decoder R9 form) + ONE zero-risk change: decoder K-loops get a
// depth-1 register double-buffer pipeline (load c+1's weights/activations
// before c's MFMA cluster, peeled last iteration). Pure dataflow reorder,
// bit-identical accumulation -> absmax unchanged; cannot race.
// Decision context: totals show a ~380us harness floor (gates +-30us moved
// totals only +-7 across R4/R6/R8/R14); this is the last additive candidate
// below the floor. If total stays >=379, declare convergence next round.
// FRAG(K) addr(row,k) = (row>>4)*16K + (k>>5)*512 + ((k>>3)&3)*128
//                       + (row&15)*8 + (k&7)   [halves]
// ---------------------------------------------------------------------------

typedef _Float16 half_t;
typedef _Float16 half8 __attribute__((ext_vector_type(8)));
typedef _Float16 half4v __attribute__((ext_vector_type(4)));
typedef float float4v __attribute__((ext_vector_type(4)));

#define GLD_LDS16(gptr, lptr)                                                  \
  __builtin_amdgcn_global_load_lds(                                            \
      (const __attribute__((address_space(1))) void*)(gptr),                   \
      (__attribute__((address_space(3))) void*)(lptr), 16, 0, 0)

__device__ __forceinline__ float fsig(float x) {
  return 1.0f / (1.0f + __expf(-x));
}
__device__ __forceinline__ float ftanh_(float x) {
  const float e = __expf(2.0f * x);
  return 1.0f - 2.0f / (e + 1.0f);
}

// ---------------------------------------------------------------------------
// Gates GEMM with fused LSTM epilogue. (R7 structure, measured 170.6us.
// FROZEN — do not deviate: R8/R11/R12/R13 all regressed.)
// 256x256 tile, BK=32, 512 threads (8 waves, 2M x 4N of 128x64 each).
// LDS: 3 buffers x (A 16KB + B 16KB) = 96 KB. Prefetch distance 2 K-tiles;
// counted vmcnt(4); 2 phases/K-tile with 4 barriers (fine interleave).
// Writes h_out (f32 row-major) and H2F (f16, FRAG(1024) order).
// ---------------------------------------------------------------------------
__global__ __launch_bounds__(512, 2) void gemm_gates(const half_t* __restrict__ A,
                                                     const half_t* __restrict__ Bw,
                                                     const float* __restrict__ bias,
                                                     const float* __restrict__ cin,
                                                     float* __restrict__ hout,
                                                     half_t* __restrict__ h2f) {
  constexpr int K = 2048;
  constexpr int NT = 64;  // K / 32
  __shared__ alignas(16) half_t As[3][256 * 32];
  __shared__ alignas(16) half_t Bs[3][256 * 32];
  const int tid = threadIdx.x;
  const int lane = tid & 63;
  const int wave = tid >> 6;
  const int m = lane & 15;
  const int q = lane >> 4;
  const int ks = (q ^ ((m >> 1) & 3)) << 3;  // swizzled k-chunk (halves)
  const int wm = (wave >> 2) << 7;           // 0 / 128
  const int wn = (wave & 3) << 6;            // 0 / 64 / 128 / 192

  const int bid = blockIdx.x;
  const int xcd = bid & 7;
  const int l = bid >> 3;  // 0..63
  const size_t tile_n = (size_t)((xcd << 1) | (l & 1)) << 8;
  const size_t tile_m = (size_t)(l >> 1) << 8;

  const int ci0 = tid, ci1 = tid + 512;
  const int r0 = ci0 >> 2, k0s = (ci0 & 3) ^ ((r0 >> 1) & 3);
  const int r1 = ci1 >> 2, k1s = (ci1 & 3) ^ ((r1 >> 1) & 3);
  const half_t* Ag0 = A + (tile_m + r0) * (size_t)K + k0s * 8;
  const half_t* Ag1 = A + (tile_m + r1) * (size_t)K + k1s * 8;
  const half_t* Bg0 = Bw + (tile_n + r0) * (size_t)K + k0s * 8;
  const half_t* Bg1 = Bw + (tile_n + r1) * (size_t)K + k1s * 8;
  const int p0 = ci0 * 16, p1 = ci1 * 16;

  // prologue: stage K-tiles 0 and 1; wait only for tile 0 (vmcnt(4)).
  GLD_LDS16(Ag0, (char*)As[0] + p0);
  GLD_LDS16(Ag1, (char*)As[0] + p1);
  GLD_LDS16(Bg0, (char*)Bs[0] + p0);
  GLD_LDS16(Bg1, (char*)Bs[0] + p1);
  GLD_LDS16(Ag0 + 32, (char*)As[1] + p0);
  GLD_LDS16(Ag1 + 32, (char*)As[1] + p1);
  GLD_LDS16(Bg0 + 32, (char*)Bs[1] + p0);
  GLD_LDS16(Bg1 + 32, (char*)Bs[1] + p1);
  asm volatile("s_waitcnt vmcnt(4)" ::: "memory");
  __builtin_amdgcn_s_barrier();
  __builtin_amdgcn_sched_barrier(0);

  float4v acc[8][4] = {};
  int bc = 0;  // buffer of current K-tile
  for (int t = 0; t < NT; ++t) {
    const half_t* as = As[bc];
    const half_t* bs = Bs[bc];
    const int bst = (bc + 2 >= 3) ? bc - 1 : bc + 2;  // (bc+2)%3
    const size_t koff = (size_t)(t + 2) * 32;
    half8 af[4], bf[4];
    // ---- phase 0: rows [wm, wm+64) x all 4 n-frags ----
#pragma unroll
    for (int i = 0; i < 4; ++i)
      af[i] = *(const half8*)(as + (wm + i * 16 + m) * 32 + ks);
#pragma unroll
    for (int j = 0; j < 4; ++j)
      bf[j] = *(const half8*)(bs + (wn + j * 16 + m) * 32 + ks);
    if (t < NT - 2) {
      GLD_LDS16(Ag0 + koff, (char*)As[bst] + p0);
      GLD_LDS16(Ag1 + koff, (char*)As[bst] + p1);
    }
    __builtin_amdgcn_s_barrier();
    asm volatile("s_waitcnt lgkmcnt(0)" ::: "memory");
    __builtin_amdgcn_sched_barrier(0);  // rule 18: pin MFMA below the wait
    __builtin_amdgcn_s_setprio(1);
#pragma unroll
    for (int i = 0; i < 4; ++i)
#pragma unroll
      for (int j = 0; j < 4; ++j)
        acc[i][j] = __builtin_amdgcn_mfma_f32_16x16x32_f16(af[i], bf[j],
                                                           acc[i][j], 0, 0, 0);
    __builtin_amdgcn_s_setprio(0);
    __builtin_amdgcn_s_barrier();
    __builtin_amdgcn_sched_barrier(0);
    // ---- phase 1: rows [wm+64, wm+128) x all 4 n-frags (bf reused) ----
    half8 ag[4];
#pragma unroll
    for (int i = 0; i < 4; ++i)
      ag[i] = *(const half8*)(as + (wm + 64 + i * 16 + m) * 32 + ks);
    if (t < NT - 2) {
      GLD_LDS16(Bg0 + koff, (char*)Bs[bst] + p0);
      GLD_LDS16(Bg1 + koff, (char*)Bs[bst] + p1);
    }
    __builtin_amdgcn_s_barrier();
    asm volatile("s_waitcnt lgkmcnt(0)" ::: "memory");
    __builtin_amdgcn_sched_barrier(0);
    __builtin_amdgcn_s_setprio(1);
#pragma unroll
    for (int i = 0; i < 4; ++i)
#pragma unroll
      for (int j = 0; j < 4; ++j)
        acc[4 + i][j] = __builtin_amdgcn_mfma_f32_16x16x32_f16(
            ag[i], bf[j], acc[4 + i][j], 0, 0, 0);
    __builtin_amdgcn_s_setprio(0);
    // counted per-tile wait: tile t+1 landed, tile t+2 stays in flight.
    if (t < NT - 2) {
      asm volatile("s_waitcnt vmcnt(4)" ::: "memory");
    } else if (t == NT - 2) {
      asm volatile("s_waitcnt vmcnt(0)" ::: "memory");
    }
    __builtin_amdgcn_s_barrier();
    __builtin_amdgcn_sched_barrier(0);
    bc = (bc + 1 == 3) ? 0 : bc + 1;
  }

  // fused LSTM epilogue (C/D: col=lane&15, row=q*4+reg [m89])
  const int nwave = (int)tile_n + wn;
  const int u = ((nwave >> 6) << 4) + m;  // hidden unit index
  const int rtb = (int)((tile_m + wm) >> 4);
  const int ubase = (u >> 5) * 512 + ((u >> 3) & 3) * 128 + (u & 7);
  float bg[4];
#pragma unroll
  for (int g = 0; g < 4; ++g) bg[g] = bias[nwave + g * 16 + m];
#pragma unroll
  for (int i = 0; i < 8; ++i) {
#pragma unroll
    for (int r = 0; r < 4; ++r) {
      const size_t row = tile_m + wm + q * 4 + i * 16 + r;
      const size_t off = row * 1024 + u;
      const float F = fsig(acc[i][0][r] + bg[0]);
      const float I = fsig(acc[i][1][r] + bg[1]);
      const float S = ftanh_(acc[i][2][r] + bg[2]);
      const float O = fsig(acc[i][3][r] + bg[3]);
      const float cn = cin[off] * F + I * S;
      const float hn = O * ftanh_(cn);
      hout[off] = hn;
      h2f[(size_t)(rtb + i) * 16384 + ubase + (q * 4 + r) * 8] = (half_t)hn;
    }
  }
}

// ---------------------------------------------------------------------------
// Fused decoder: dec1(1024->512,tanh) + dec2(512->384,tanh) +
// dec3(384->512) + softmax. 32 batch rows per block, 256 blocks (1/CU).
// R15: each K-loop software-pipelined depth-1 (reg double-buffer, peeled
// last iteration). Same MFMA order -> bit-identical results.
// Activations in LDS: A1 64KB -> A2 32KB -> A3 24KB; logits alias A1.
// Weights pre-packed B-FRAG -> coalesced 1KB wave reads.
// ---------------------------------------------------------------------------
__global__ __launch_bounds__(512, 2) void fused_decoder(
    const half_t* __restrict__ h2f,  // FRAG(1024), 512 row-tiles
    const half_t* __restrict__ W1f,  // BFRAG(1024): 32 col-tiles x 16384
    const float* __restrict__ b1,    // [512]
    const half_t* __restrict__ W2f,  // BFRAG(512):  24 col-tiles x 8192
    const float* __restrict__ b2,    // [384] (padded, zeros past 341)
    const half_t* __restrict__ W3f,  // BFRAG(384):  32 col-tiles x 6144
    const float* __restrict__ b3,    // [512]
    float* __restrict__ out) {       // [8192][512] f32
  __shared__ alignas(16) half_t A1s[2 * 16384];  // 64KB (aliased by logits)
  __shared__ alignas(16) half_t A2s[2 * 8192];   // 32KB
  __shared__ alignas(16) half_t A3s[2 * 6144];   // 24KB
  float* LOGL = (float*)A1s;                     // [32][512] f32

  const int tid = threadIdx.x;
  const int lane = tid & 63;
  const int w = tid >> 6;  // wave 0..7
  const int m = lane & 15;
  const int q = lane >> 4;
  const int b = blockIdx.x;  // rows b*32 .. b*32+31 (row-tiles 2b, 2b+1)

  // ---- stage A1: 64KB contiguous from H2F (FRAG order preserved) ----
  const half_t* src = h2f + (size_t)b * 32768;
#pragma unroll
  for (int it = 0; it < 8; ++it)
    GLD_LDS16(src + (it * 512 + tid) * 8, (char*)A1s + (it * 512 + tid) * 16);
  asm volatile("s_waitcnt vmcnt(0)" ::: "memory");
  __syncthreads();

  // ---- dec1: K=1024, wave cols [w*64, w*64+64) ----
  {
    float4v acc[2][4] = {};
    const half_t* w1 = W1f + (size_t)(w * 4) * 16384 + lane * 8;
    half8 wfA[4], afA[2];
#pragma unroll
    for (int j = 0; j < 4; ++j) wfA[j] = *(const half8*)(w1 + j * 16384);
#pragma unroll
    for (int rt = 0; rt < 2; ++rt)
      afA[rt] = *(const half8*)(A1s + rt * 16384 + q * 128 + m * 8);
#pragma unroll 2
    for (int c = 0; c < 31; ++c) {
      half8 wfB[4], afB[2];
#pragma unroll
      for (int j = 0; j < 4; ++j)
        wfB[j] = *(const half8*)(w1 + j * 16384 + (c + 1) * 512);
#pragma unroll
      for (int rt = 0; rt < 2; ++rt)
        afB[rt] = *(const half8*)(A1s + rt * 16384 + (c + 1) * 512 + q * 128 + m * 8);
#pragma unroll
      for (int rt = 0; rt < 2; ++rt)
#pragma unroll
        for (int j = 0; j < 4; ++j)
          acc[rt][j] = __builtin_amdgcn_mfma_f32_16x16x32_f16(afA[rt], wfA[j],
                                                              acc[rt][j], 0, 0, 0);
#pragma unroll
      for (int j = 0; j < 4; ++j) wfA[j] = wfB[j];
#pragma unroll
      for (int rt = 0; rt < 2; ++rt) afA[rt] = afB[rt];
    }
#pragma unroll
    for (int rt = 0; rt < 2; ++rt)
#pragma unroll
      for (int j = 0; j < 4; ++j)
        acc[rt][j] = __builtin_amdgcn_mfma_f32_16x16x32_f16(afA[rt], wfA[j],
                                                            acc[rt][j], 0, 0, 0);
    // epilogue: tanh + bias -> A2 (FRAG(512))
#pragma unroll
    for (int j = 0; j < 4; ++j) {
      const int col = w * 64 + j * 16 + m;
      const float bv = b1[col];
      const int cb = (col >> 5) * 512 + ((col >> 3) & 3) * 128 + (col & 7);
#pragma unroll
      for (int rt = 0; rt < 2; ++rt)
#pragma unroll
        for (int r = 0; r < 4; ++r)
          A2s[rt * 8192 + cb + (q * 4 + r) * 8] = (half_t)ftanh_(acc[rt][j][r] + bv);
    }
  }
  __syncthreads();

  // ---- dec2: K=512, wave cols [w*48, w*48+48) ----
  {
    float4v acc[2][3] = {};
    const half_t* w2 = W2f + (size_t)(w * 3) * 8192 + lane * 8;
    half8 wfA[3], afA[2];
#pragma unroll
    for (int j = 0; j < 3; ++j) wfA[j] = *(const half8*)(w2 + j * 8192);
#pragma unroll
    for (int rt = 0; rt < 2; ++rt)
      afA[rt] = *(const half8*)(A2s + rt * 8192 + q * 128 + m * 8);
#pragma unroll 2
    for (int c = 0; c < 15; ++c) {
      half8 wfB[3], afB[2];
#pragma unroll
      for (int j = 0; j < 3; ++j)
        wfB[j] = *(const half8*)(w2 + j * 8192 + (c + 1) * 512);
#pragma unroll
      for (int rt = 0; rt < 2; ++rt)
        afB[rt] = *(const half8*)(A2s + rt * 8192 + (c + 1) * 512 + q * 128 + m * 8);
#pragma unroll
      for (int rt = 0; rt < 2; ++rt)
#pragma unroll
        for (int j = 0; j < 3; ++j)
          acc[rt][j] = __builtin_amdgcn_mfma_f32_16x16x32_f16(afA[rt], wfA[j],
                                                              acc[rt][j], 0, 0, 0);
#pragma unroll
      for (int j = 0; j < 3; ++j) wfA[j] = wfB[j];
#pragma unroll
      for (int rt = 0; rt < 2; ++rt) afA[rt] = afB[rt];
    }
#pragma unroll
    for (int rt = 0; rt < 2; ++rt)
#pragma unroll
      for (int j = 0; j < 3; ++j)
        acc[rt][j] = __builtin_amdgcn_mfma_f32_16x16x32_f16(afA[rt], wfA[j],
                                                            acc[rt][j], 0, 0, 0);
    // epilogue: tanh + bias -> A3 (FRAG(384)); pad cols produce tanh(0)=0
#pragma unroll
    for (int j = 0; j < 3; ++j) {
      const int col = w * 48 + j * 16 + m;
      const float bv = b2[col];
      const int cb = (col >> 5) * 512 + ((col >> 3) & 3) * 128 + (col & 7);
#pragma unroll
      for (int rt = 0; rt < 2; ++rt)
#pragma unroll
        for (int r = 0; r < 4; ++r)
          A3s[rt * 6144 + cb + (q * 4 + r) * 8] = (half_t)ftanh_(acc[rt][j][r] + bv);
    }
  }
  __syncthreads();

  // ---- dec3: K=384, wave cols [w*64, w*64+64) -> logits f32 in LDS ----
  {
    float4v acc[2][4] = {};
    const half_t* w3 = W3f + (size_t)(w * 4) * 6144 + lane * 8;
    half8 wfA[4], afA[2];
#pragma unroll
    for (int j = 0; j < 4; ++j) wfA[j] = *(const half8*)(w3 + j * 6144);
#pragma unroll
    for (int rt = 0; rt < 2; ++rt)
      afA[rt] = *(const half8*)(A3s + rt * 6144 + q * 128 + m * 8);
#pragma unroll 2
    for (int c = 0; c < 11; ++c) {
      half8 wfB[4], afB[2];
#pragma unroll
      for (int j = 0; j < 4; ++j)
        wfB[j] = *(const half8*)(w3 + j * 6144 + (c + 1) * 512);
#pragma unroll
      for (int rt = 0; rt < 2; ++rt)
        afB[rt] = *(const half8*)(A3s + rt * 6144 + (c + 1) * 512 + q * 128 + m * 8);
#pragma unroll
      for (int rt = 0; rt < 2; ++rt)
#pragma unroll
        for (int j = 0; j < 4; ++j)
          acc[rt][j] = __builtin_amdgcn_mfma_f32_16x16x32_f16(afA[rt], wfA[j],
                                                              acc[rt][j], 0, 0, 0);
#pragma unroll
      for (int j = 0; j < 4; ++j) wfA[j] = wfB[j];
#pragma unroll
      for (int rt = 0; rt < 2; ++rt) afA[rt] = afB[rt];
    }
#pragma unroll
    for (int rt = 0; rt < 2; ++rt)
#pragma unroll
      for (int j = 0; j < 4; ++j)
        acc[rt][j] = __builtin_amdgcn_mfma_f32_16x16x32_f16(afA[rt], wfA[j],
                                                            acc[rt][j], 0, 0, 0);
    // LOGL aliases A1s: A1s dead since dec1 (2 barriers ago).
#pragma unroll
    for (int j = 0; j < 4; ++j) {
      const int col = w * 64 + j * 16 + m;
      const float bv = b3[col];
#pragma unroll
      for (int rt = 0; rt < 2; ++rt)
#pragma unroll
        for (int r = 0; r < 4; ++r)
          LOGL[(rt * 16 + q * 4 + r) * 512 + col] = acc[rt][j][r] + bv;
    }
  }
  __syncthreads();

  // ---- softmax over 512 cols: wave w handles rows w*4 .. w*4+3 ----
#pragma unroll
  for (int rr = 0; rr < 4; ++rr) {
    const int row = w * 4 + rr;
    const float4v* srcv = (const float4v*)(LOGL + row * 512);
    const float4v v0 = srcv[lane * 2];
    const float4v v1 = srcv[lane * 2 + 1];
    float mx = fmaxf(fmaxf(fmaxf(v0.x, v0.y), fmaxf(v0.z, v0.w)),
                     fmaxf(fmaxf(v1.x, v1.y), fmaxf(v1.z, v1.w)));
#pragma unroll
    for (int off = 32; off > 0; off >>= 1) mx = fmaxf(mx, __shfl_xor(mx, off, 64));
    const float e0 = __expf(v0.x - mx), e1 = __expf(v0.y - mx);
    const float e2 = __expf(v0.z - mx), e3 = __expf(v0.w - mx);
    const float e4 = __expf(v1.x - mx), e5 = __expf(v1.y - mx);
    const float e6 = __expf(v1.z - mx), e7 = __expf(v1.w - mx);
    float sum = ((e0 + e1) + (e2 + e3)) + ((e4 + e5) + (e6 + e7));
#pragma unroll
    for (int off = 32; off > 0; off >>= 1) sum += __shfl_xor(sum, off, 64);
    const float inv = 1.0f / sum;
    float4v o0, o1;
    o0.x = e0 * inv; o0.y = e1 * inv; o0.z = e2 * inv; o0.w = e3 * inv;
    o1.x = e4 * inv; o1.y = e5 * inv; o1.z = e6 * inv; o1.w = e7 * inv;
    float4v* dst = (float4v*)(out + ((size_t)b * 32 + row) * 512);
    dst[lane * 2] = o0;
    dst[lane * 2 + 1] = o1;
  }
}

// ---------------------------------------------------------------------------
// prep_all: single prep launch (prep_pack + prep_small merged).
// blocks [0,16384)      -> XH f16 [8192,2048]
// blocks [16384,24576)  -> WALL f16 (gate weights interleaved)
// blocks [24576,25490)  -> decoder weights B-FRAG + biases
// BFRAG(K) addr(col,k) = (col>>4)*16K + (k>>5)*512 + ((k>>3)&3)*128
//                        + (col&15)*8 + (k&7)   [halves]
// ---------------------------------------------------------------------------
__global__ void prep_all(const float* __restrict__ x, const float* __restrict__ h,
                         const float* __restrict__ Wfi, const float* __restrict__ Wfh,
                         const float* __restrict__ Wii, const float* __restrict__ Wih,
                         const float* __restrict__ Wsi, const float* __restrict__ Wsh,
                         const float* __restrict__ Woi, const float* __restrict__ Woh,
                         const float* __restrict__ Wd1, const float* __restrict__ Wd2,
                         const float* __restrict__ Wd3, const float* __restrict__ bd2,
                         const float* __restrict__ bfi, const float* __restrict__ bfh,
                         const float* __restrict__ bii, const float* __restrict__ bih,
                         const float* __restrict__ bsi, const float* __restrict__ bsh,
                         const float* __restrict__ boi, const float* __restrict__ boh,
                         half_t* __restrict__ xh, half_t* __restrict__ wall,
                         half_t* __restrict__ WD1, half_t* __restrict__ WD2h,
                         half_t* __restrict__ WD3h, float* __restrict__ BALL,
                         float* __restrict__ BD2) {
  const int bid = blockIdx.x;
  const int tid = threadIdx.x;
  if (bid < 24576) {
    const float* src;
    half_t* dst;
    size_t idx;
    if (bid < 16384) {
      idx = ((size_t)bid * 256 + tid) * 4;
      const size_t bb = idx >> 11;
      const int col = (int)(idx & 2047);
      src = (col < 1024) ? (x + bb * 1024 + col) : (h + bb * 1024 + (col - 1024));
      dst = xh + idx;
    } else {
      idx = ((size_t)(bid - 16384) * 256 + tid) * 4;
      const int n = (int)(idx >> 11);
      const int col = (int)(idx & 2047);
      const int g = (n >> 4) & 3;
      const size_t u = (size_t)(((n >> 6) << 4) | (n & 15));
      const float* Wi = (g == 0) ? Wfi : (g == 1) ? Wii : (g == 2) ? Wsi : Woi;
      const float* Wh = (g == 0) ? Wfh : (g == 1) ? Wih : (g == 2) ? Wsh : Woh;
      src = (col < 1024) ? (Wi + u * 1024 + col) : (Wh + u * 1024 + (col - 1024));
      dst = wall + idx;
    }
    const float4v v = *(const float4v*)src;
    half4v o;
    o.x = (half_t)v.x; o.y = (half_t)v.y; o.z = (half_t)v.z; o.w = (half_t)v.w;
    *(half4v*)dst = o;
    return;
  }
  const int b2i = bid - 24576;  // 0..913
  if (b2i < 512) {
    // WD1: 512x1024 -> BFRAG(1024)
    const size_t i4 = ((size_t)b2i * 256 + tid) * 4;
    const int col = (int)(i4 >> 10);
    const int k0 = (int)(i4 & 1023);
    const float4v v = *(const float4v*)(Wd1 + i4);
    half4v o;
    o.x = (half_t)v.x; o.y = (half_t)v.y; o.z = (half_t)v.z; o.w = (half_t)v.w;
    const size_t fa = (size_t)(col >> 4) * 16384 + (k0 >> 5) * 512 +
                      ((k0 >> 3) & 3) * 128 + (col & 15) * 8 + (k0 & 7);
    *(half4v*)(WD1 + fa) = o;
  } else if (b2i < 704) {
    // WD2: 384x512 (rows>=341 zero) -> BFRAG(512)
    const size_t i4 = ((size_t)(b2i - 512) * 256 + tid) * 4;
    const int col = (int)(i4 >> 9);
    const int k0 = (int)(i4 & 511);
    half4v o;
    if (col < 341) {
      const float4v v = *(const float4v*)(Wd2 + (size_t)col * 512 + k0);
      o.x = (half_t)v.x; o.y = (half_t)v.y; o.z = (half_t)v.z; o.w = (half_t)v.w;
    } else {
      o.x = (half_t)0.f; o.y = (half_t)0.f; o.z = (half_t)0.f; o.w = (half_t)0.f;
    }
    const size_t fa = (size_t)(col >> 4) * 8192 + (k0 >> 5) * 512 +
                      ((k0 >> 3) & 3) * 128 + (col & 15) * 8 + (k0 & 7);
    *(half4v*)(WD2h + fa) = o;
  } else if (b2i < 896) {
    // WD3: 512x384 (k>=341 zero) -> BFRAG(384)
    const size_t i4 = ((size_t)(b2i - 704) * 256 + tid) * 4;
    const int col = (int)(i4 / 384);
    const int k0 = (int)(i4 - (size_t)col * 384);
    half4v o;
    o.x = (k0 + 0 < 341) ? (half_t)Wd3[(size_t)col * 341 + k0 + 0] : (half_t)0.f;
    o.y = (k0 + 1 < 341) ? (half_t)Wd3[(size_t)col * 341 + k0 + 1] : (half_t)0.f;
    o.z = (k0 + 2 < 341) ? (half_t)Wd3[(size_t)col * 341 + k0 + 2] : (half_t)0.f;
    o.w = (k0 + 3 < 341) ? (half_t)Wd3[(size_t)col * 341 + k0 + 3] : (half_t)0.f;
    const size_t fa = (size_t)(col >> 4) * 6144 + (k0 >> 5) * 512 +
                      ((k0 >> 3) & 3) * 128 + (col & 15) * 8 + (k0 & 7);
    *(half4v*)(WD3h + fa) = o;
  } else if (b2i < 912) {
    const int n = (b2i - 896) * 256 + tid;
    const int g = (n >> 4) & 3;
    const int u = ((n >> 6) << 4) | (n & 15);
    const float* bi = (g == 0) ? bfi : (g == 1) ? bii : (g == 2) ? bsi : boi;
    const float* bh = (g == 0) ? bfh : (g == 1) ? bih : (g == 2) ? bsh : boh;
    BALL[n] = bi[u] + bh[u];
  } else {
    const int i = (b2i - 912) * 256 + tid;
    if (i < 384) BD2[i] = (i < 341) ? bd2[i] : 0.0f;
  }
}

// ---------------------------------------------------------------------------
extern "C" void kernel_launch(void* const* d_in, const int* in_sizes, int n_in,
                              void* d_out, int out_size, void* d_ws, size_t ws_size,
                              hipStream_t stream) {
  const float* x = (const float*)d_in[0];
  const float* h = (const float*)d_in[1];
  const float* c = (const float*)d_in[2];
  const float* Wfi = (const float*)d_in[3];  const float* bfi = (const float*)d_in[4];
  const float* Wfh = (const float*)d_in[5];  const float* bfh = (const float*)d_in[6];
  const float* Wii = (const float*)d_in[7];  const float* bii = (const float*)d_in[8];
  const float* Wih = (const float*)d_in[9];  const float* bih = (const float*)d_in[10];
  const float* Wsi = (const float*)d_in[11]; const float* bsi = (const float*)d_in[12];
  const float* Wsh = (const float*)d_in[13]; const float* bsh = (const float*)d_in[14];
  const float* Woi = (const float*)d_in[15]; const float* boi = (const float*)d_in[16];
  const float* Woh = (const float*)d_in[17]; const float* boh = (const float*)d_in[18];
  const float* Wd1 = (const float*)d_in[19]; const float* bd1 = (const float*)d_in[20];
  const float* Wd2 = (const float*)d_in[21]; const float* bd2 = (const float*)d_in[22];
  const float* Wd3 = (const float*)d_in[23]; const float* bd3 = (const float*)d_in[24];

  char* ws = (char*)d_ws;
  size_t o = 0;
  auto alloc = [&](size_t bytes) {
    size_t cur = o;
    o += (bytes + 255) & ~(size_t)255;
    return cur;
  };
  half_t* XH   = (half_t*)(ws + alloc((size_t)8192 * 2048 * 2));  // 33.5 MB
  half_t* WALL = (half_t*)(ws + alloc((size_t)4096 * 2048 * 2));  // 16.8 MB
  float*  BALL = (float*)(ws + alloc(4096 * 4));
  half_t* WD1  = (half_t*)(ws + alloc((size_t)512 * 1024 * 2));   // BFRAG(1024)
  half_t* WD2  = (half_t*)(ws + alloc((size_t)384 * 512 * 2));    // BFRAG(512)
  float*  BD2  = (float*)(ws + alloc(384 * 4));
  half_t* WD3  = (half_t*)(ws + alloc((size_t)512 * 384 * 2));    // BFRAG(384)
  half_t* H2F  = (half_t*)(ws + alloc((size_t)8192 * 1024 * 2));  // 16.8 MB frag

  float* h_out = (float*)d_out;                          // [8192,1024] f32
  float* d_outp = (float*)d_out + (size_t)8192 * 1024;   // [8192,512] f32

  // single prep launch (inputs re-poisoned every call, so convert every call)
  prep_all<<<25490, 256, 0, stream>>>(x, h, Wfi, Wfh, Wii, Wih, Wsi, Wsh, Woi, Woh,
                                      Wd1, Wd2, Wd3, bd2, bfi, bfh, bii, bih, bsi,
                                      bsh, boi, boh, XH, WALL, WD1, WD2, WD3, BALL,
                                      BD2);

  // gates GEMM + fused LSTM -> h_out (f32) + H2F (f16 frag order)
  gemm_gates<<<512, 512, 0, stream>>>(XH, WALL, BALL, c, h_out, H2F);

  // fused decoder: dec1+dec2+dec3+softmax, one launch, 1 block/CU
  fused_decoder<<<256, 512, 0, stream>>>(H2F, WD1, bd1, WD2, BD2, WD3, bd3, d_outp);
}